// Round 2
// baseline (168.054 us; speedup 1.0000x reference)
//
#include <hip/hip_runtime.h>

// Problem constants (match reference)
#define BB 32
#define TT 200
#define RR 4096
#define CC 81
#define IOU_THRESH 0.7f
#define RED 16.0f

#define BLK 256
#define PPB 128          // proposals per block (2 threads per proposal)
#define HALF_T 100       // each chunk scans 100 GT boxes
#define NBLOCKS (BB * (RR / PPB))   // 32 * 32 = 1024

// ws layout (floats): [0]=npos, [1]=sum_ce, [2]=sum_acc, [3]=sum_reg, [4]=block counter (uint)
__global__ __launch_bounds__(BLK) void rcnn_main_kernel(
    const float* __restrict__ nms_reg,   // [B,R,4]
    const float* __restrict__ rcnn_reg,  // [B,R,4]
    const float* __restrict__ rcnn_cls,  // [B,R,C]
    const float* __restrict__ bboxes,    // [B,T,4]
    const int*   __restrict__ classes,   // [B,T]
    float* __restrict__ ws,
    float* __restrict__ out)
{
    __shared__ float4 s_box[TT];          // GT boxes, one float4 per box
    __shared__ int    s_cls[TT];
    __shared__ float  s_c1n[PPB];         // chunk-1 candidate: numerator (inter)
    __shared__ float  s_c1d[PPB];         // denominator (union)
    __shared__ int    s_c1t[PPB];         // index
    __shared__ float  s_red[4][4];        // [wave][component]

    const int tid   = threadIdx.x;
    const int blocks_per_b = RR / PPB;    // 32
    const int b     = blockIdx.x / blocks_per_b;
    const int p     = tid & (PPB - 1);    // proposal slot within block
    const int chunk = tid >> 7;           // 0: t in [0,100), 1: t in [100,200)
    const int r     = (blockIdx.x % blocks_per_b) * PPB + p;

    // Stage this batch's GT boxes + classes into LDS (vectorized)
    const float4* gbox = (const float4*)&bboxes[(long)b * TT * 4];
    for (int i = tid; i < TT; i += BLK) {
        s_box[i] = gbox[i];
        s_cls[i] = classes[b * TT + i];
    }
    __syncthreads();

    // Proposal box
    const float4 a = ((const float4*)nms_reg)[(long)b * RR + r];
    const float area_a = (a.z - a.x) * (a.w - a.y);

    // Rational running-argmax over this chunk's T range (no divide).
    // Invariant: best iou = bn/bd; bd > 0 after first iteration.
    float bn = -1.0f, bd = 1.0f;
    int   bt = 0;
    const int tbeg = chunk * HALF_T;
    #pragma unroll 4
    for (int t = tbeg; t < tbeg + HALF_T; ++t) {
        const float4 g = s_box[t];
        const float it = fmaxf(a.x, g.x);
        const float il = fmaxf(a.y, g.y);
        const float ib = fminf(a.z, g.z);
        const float ir = fminf(a.w, g.w);
        const float inter = fmaxf(ib - it, 0.0f) * fmaxf(ir - il, 0.0f);
        const float uni   = area_a + (g.z - g.x) * (g.w - g.y) - inter;
        // inter/uni > bn/bd  <=>  inter*bd > bn*uni   (uni,bd > 0)
        const bool better = inter * bd > bn * uni;
        bn = better ? inter : bn;
        bd = better ? uni   : bd;
        bt = better ? t     : bt;
    }

    if (chunk == 1) { s_c1n[p] = bn; s_c1d[p] = bd; s_c1t[p] = bt; }
    __syncthreads();

    float pos = 0.0f, ce = 0.0f, acc = 0.0f, reg = 0.0f;
    if (chunk == 0) {
        // Combine with chunk 1's candidate; chunk 0 (lower t) wins ties.
        const float n1 = s_c1n[p];
        const float d1 = s_c1d[p];
        const int   t1 = s_c1t[p];
        if (n1 * bd > bn * d1) { bn = n1; bd = d1; bt = t1; }

        // mask: iou > 0.7  <=>  inter > 0.7 * union
        if (bn > IOU_THRESH * bd) {
            pos = 1.0f;

            // ---- regression target + SmoothL1 (summed over 4 coords) ----
            const float4 g = s_box[bt];
            const float rt = rintf(g.x / RED) * RED;  // round-half-even == jnp.round
            const float rl = rintf(g.y / RED) * RED;
            const float rb = rintf(g.z / RED) * RED;
            const float rr = rintf(g.w / RED) * RED;
            float h = rb - rt; if (h == 0.0f) h = 1.0f;
            float w = rr - rl; if (w == 0.0f) w = 1.0f;
            const float t0 = (g.x - rt) / h;
            const float t1f = (g.y - rl) / w;
            const float t2 = (g.z - rb) / h;
            const float t3 = (g.w - rr) / w;

            const float4 pr = ((const float4*)rcnn_reg)[(long)b * RR + r];
            const float d0 = fabsf(pr.x - t0);
            const float d1f = fabsf(pr.y - t1f);
            const float d2 = fabsf(pr.z - t2);
            const float d3 = fabsf(pr.w - t3);
            reg  = (d0  < 1.0f) ? 0.5f * d0  * d0  : d0  - 0.5f;
            reg += (d1f < 1.0f) ? 0.5f * d1f * d1f : d1f - 0.5f;
            reg += (d2  < 1.0f) ? 0.5f * d2  * d2  : d2  - 0.5f;
            reg += (d3  < 1.0f) ? 0.5f * d3  * d3  : d3  - 0.5f;

            // ---- CE + accuracy over C=81 (only positives touch rcnn_cls) ----
            const float* row = &rcnn_cls[((long)b * RR + r) * CC];
            const int cls = s_cls[bt];
            float m = -INFINITY;
            int amax = 0;
            #pragma unroll 9
            for (int c = 0; c < CC; ++c) {
                const float x = row[c];
                if (x > m) { m = x; amax = c; }  // strict > -> first max, matches jnp.argmax
            }
            float s = 0.0f;
            #pragma unroll 9
            for (int c = 0; c < CC; ++c) s += __expf(row[c] - m);
            ce  = m + __logf(s) - row[cls];
            acc = (amax == cls) ? 1.0f : 0.0f;
        }
    }

    // ---- wave (64-lane) shuffle reduction (chunk-1 threads contribute 0) ----
    #pragma unroll
    for (int off = 32; off > 0; off >>= 1) {
        pos += __shfl_down(pos, off);
        ce  += __shfl_down(ce,  off);
        acc += __shfl_down(acc, off);
        reg += __shfl_down(reg, off);
    }
    const int wave = tid >> 6;
    if ((tid & 63) == 0) {
        s_red[wave][0] = pos;
        s_red[wave][1] = ce;
        s_red[wave][2] = acc;
        s_red[wave][3] = reg;
    }
    __syncthreads();
    if (tid == 0) {
        float P = 0.0f, E = 0.0f, A = 0.0f, G = 0.0f;
        #pragma unroll
        for (int v = 0; v < 4; ++v) {
            P += s_red[v][0];
            E += s_red[v][1];
            A += s_red[v][2];
            G += s_red[v][3];
        }
        atomicAdd(&ws[0], P);
        atomicAdd(&ws[1], E);
        atomicAdd(&ws[2], A);
        atomicAdd(&ws[3], G);
        __threadfence();
        unsigned int* cnt = (unsigned int*)&ws[4];
        const unsigned int old = atomicAdd(cnt, 1u);
        if (old == (unsigned int)(gridDim.x - 1)) {
            // Trailing block: device-scope atomic reads for coherence across XCDs
            const float npos = atomicAdd(&ws[0], 0.0f);
            const float sce  = atomicAdd(&ws[1], 0.0f);
            const float sac  = atomicAdd(&ws[2], 0.0f);
            const float srg  = atomicAdd(&ws[3], 0.0f);
            const float denom = fmaxf(npos, 1.0f);
            const bool  hp = npos > 0.0f;
            out[0] = hp ? sce / denom : 0.0f;   // cls_loss
            out[1] = hp ? srg / denom : 0.0f;   // reg_loss
            out[2] = hp ? sac / denom : 0.0f;   // acc
        }
    }
}

extern "C" void kernel_launch(void* const* d_in, const int* in_sizes, int n_in,
                              void* d_out, int out_size, void* d_ws, size_t ws_size,
                              hipStream_t stream) {
    const float* nms_reg  = (const float*)d_in[0];
    // d_in[1] = nms_cls, unused by forward
    const float* rcnn_reg = (const float*)d_in[2];
    const float* rcnn_cls = (const float*)d_in[3];
    const float* bboxes   = (const float*)d_in[4];
    const int*   classes  = (const int*)d_in[5];
    float* ws  = (float*)d_ws;
    float* out = (float*)d_out;

    hipMemsetAsync(ws, 0, 8 * sizeof(float), stream);  // sums + counter
    rcnn_main_kernel<<<NBLOCKS, BLK, 0, stream>>>(
        nms_reg, rcnn_reg, rcnn_cls, bboxes, classes, ws, out);
}